// Round 6
// baseline (588.221 us; speedup 1.0000x reference)
//
#include <hip/hip_runtime.h>
#include <stdint.h>

// GridEncoder (instant-ngp hash grid), D=3, L=16, C=2, H=16, PLS=2, log2_hash=19.
// Round 6: corner-pair coalescing. Since PRIMES[0]==1, the x-corner pair rows
// are (X0^h) and ((X0+1)^h). For even X0, X0+1 == X0^1, so the two rows are
// {r, r^1} = one 16B-aligned float4 (offsets are multiples of 8 rows, so +off
// keeps alignment, and the pair never crosses a 64B line). Odd-X0 lanes load
// the second corner separately (exec-masked). Expected line requests/point:
// 4 + 0.5*4 = 6 vs 8 (-25%). Rounds 4-5 established the gather phase is
// capped by per-CU outstanding-line-request concurrency (~84 lines @ ~200cy);
// request COUNT is the only remaining lever.
// Everything else identical to round 3 (best structure: 2 pts/thread,
// blockIdx.y = level, no remap, no nt). Arithmetic and fma order unchanged
// -> bit-identical output (absmax 4.768372e-07).

#define NLEV 16

__constant__ uint32_t dOff[NLEV] = {
    0u, 4096u, 36864u, 299008u, 823296u, 1347584u, 1871872u, 2396160u,
    2920448u, 3444736u, 3969024u, 4493312u, 5017600u, 5541888u,
    6066176u, 6590464u };
__constant__ uint32_t dMask[NLEV] = {
    4095u, 32767u, 262143u, 524287u, 524287u, 524287u, 524287u, 524287u,
    524287u, 524287u, 524287u, 524287u, 524287u, 524287u, 524287u, 524287u };
__constant__ float dScale[NLEV] = {
    15.f, 31.f, 63.f, 127.f, 255.f, 511.f, 1023.f, 2047.f,
    4095.f, 8191.f, 16383.f, 32767.f, 65535.f, 131071.f, 262143.f, 524287.f };

constexpr uint32_t P1 = 2654435761u, P2 = 805459861u;

// pair[j]: 16B-aligned row (incl. off) holding corner x0 (and x1 if X0 even)
// alt[j] : row (incl. off) of corner x1, used only when X0 odd
// sel[j] : 1 if corner x0 is the hi float2 of the pair
__device__ __forceinline__ void encode_pairs(
    float x, float y, float z, float scale, uint32_t mask, uint32_t off,
    uint32_t pair[4], uint32_t alt[4], uint32_t sel[4], bool& odd, float w[8])
{
    const float px = __fadd_rn(__fmul_rn(x, scale), 0.5f);
    const float py = __fadd_rn(__fmul_rn(y, scale), 0.5f);
    const float pz = __fadd_rn(__fmul_rn(z, scale), 0.5f);
    const float fx0 = floorf(px), fy0 = floorf(py), fz0 = floorf(pz);
    const uint32_t X0 = (uint32_t)fx0;
    const uint32_t Y0 = (uint32_t)fy0;
    const uint32_t Z0 = (uint32_t)fz0;
    const float fx = px - fx0, fy = py - fy0, fz = pz - fz0;

    const uint32_t hx0 = X0,      hx1 = X0 + 1u;
    const uint32_t hy0 = Y0 * P1, hy1 = hy0 + P1;
    const uint32_t hz0 = Z0 * P2, hz1 = hz0 + P2;

    odd = (X0 & 1u) != 0u;
    const uint32_t hyz0 = hy0 ^ hz0, hyz1 = hy1 ^ hz0;
    const uint32_t hyz2 = hy0 ^ hz1, hyz3 = hy1 ^ hz1;
    const uint32_t hyz[4] = { hyz0, hyz1, hyz2, hyz3 };
    #pragma unroll
    for (int j = 0; j < 4; ++j) {
        const uint32_t r0 = (hx0 ^ hyz[j]) & mask;
        pair[j] = (r0 & ~1u) + off;
        sel[j]  = r0 & 1u;
        alt[j]  = ((hx1 ^ hyz[j]) & mask) + off;
    }

    const float wx1 = fx, wx0 = 1.0f - fx;
    const float wy1 = fy, wy0 = 1.0f - fy;
    const float wz1 = fz, wz0 = 1.0f - fz;
    const float wy0z0 = wy0 * wz0, wy1z0 = wy1 * wz0;
    const float wy0z1 = wy0 * wz1, wy1z1 = wy1 * wz1;
    w[0] = wx0 * wy0z0; w[1] = wx1 * wy0z0;
    w[2] = wx0 * wy1z0; w[3] = wx1 * wy1z0;
    w[4] = wx0 * wy0z1; w[5] = wx1 * wy0z1;
    w[6] = wx0 * wy1z1; w[7] = wx1 * wy1z1;
}

// all levels in one dispatch: blockIdx.y = level; two points per thread
__global__ __launch_bounds__(256, 8) void levels_fused_kernel(
    const float* __restrict__ inp,   // [B,3]
    const float2* __restrict__ etab, // [total_rows]
    float2* __restrict__ slab,       // [NLEV][B]
    int B)
{
    const int lvl = blockIdx.y;
    const float    scale = dScale[lvl];
    const uint32_t mask  = dMask[lvl];
    const uint32_t off   = dOff[lvl];
    float2* __restrict__ lslab = slab + (size_t)lvl * B;

    const int t = blockIdx.x * blockDim.x + threadIdx.x;
    const int half = B >> 1;
    if (t >= half) return;
    const int b0 = t, b1 = t + half;

    const float x0 = (inp[3 * b0 + 0] + 1.0f) * 0.5f;
    const float y0 = (inp[3 * b0 + 1] + 1.0f) * 0.5f;
    const float z0 = (inp[3 * b0 + 2] + 1.0f) * 0.5f;
    const float x1 = (inp[3 * b1 + 0] + 1.0f) * 0.5f;
    const float y1 = (inp[3 * b1 + 1] + 1.0f) * 0.5f;
    const float z1 = (inp[3 * b1 + 2] + 1.0f) * 0.5f;

    uint32_t p0[4], a0[4], s0[4]; bool o0; float w0[8];
    uint32_t p1[4], a1[4], s1[4]; bool o1; float w1[8];
    encode_pairs(x0, y0, z0, scale, mask, off, p0, a0, s0, o0, w0);
    encode_pairs(x1, y1, z1, scale, mask, off, p1, a1, s1, o1, w1);

    // pair loads: one float4 covers both x-corners when X0 even
    float4 P0[4], P1[4];
    #pragma unroll
    for (int j = 0; j < 4; ++j)
        P0[j] = *reinterpret_cast<const float4*>(etab + p0[j]);
    #pragma unroll
    for (int j = 0; j < 4; ++j)
        P1[j] = *reinterpret_cast<const float4*>(etab + p1[j]);

    // odd-X0 lanes fetch the x1 corner separately (exec-masked loads)
    float2 A0[4] = {make_float2(0.f,0.f), make_float2(0.f,0.f),
                    make_float2(0.f,0.f), make_float2(0.f,0.f)};
    float2 A1[4] = {make_float2(0.f,0.f), make_float2(0.f,0.f),
                    make_float2(0.f,0.f), make_float2(0.f,0.f)};
    if (o0) {
        #pragma unroll
        for (int j = 0; j < 4; ++j) A0[j] = etab[a0[j]];
    }
    if (o1) {
        #pragma unroll
        for (int j = 0; j < 4; ++j) A1[j] = etab[a1[j]];
    }

    // consume: identical weight/fma order to rounds 1-5 (corners 0..7)
    float ax0 = 0.f, ay0 = 0.f, ax1 = 0.f, ay1 = 0.f;
    #pragma unroll
    for (int j = 0; j < 4; ++j) {
        const float2 lo0 = make_float2(P0[j].x, P0[j].y);
        const float2 hi0 = make_float2(P0[j].z, P0[j].w);
        const float2 ex0_0 = s0[j] ? hi0 : lo0;
        const float2 ex1_0 = o0 ? A0[j] : (s0[j] ? lo0 : hi0);
        ax0 = fmaf(w0[2*j],   ex0_0.x, ax0);
        ay0 = fmaf(w0[2*j],   ex0_0.y, ay0);
        ax0 = fmaf(w0[2*j+1], ex1_0.x, ax0);
        ay0 = fmaf(w0[2*j+1], ex1_0.y, ay0);

        const float2 lo1 = make_float2(P1[j].x, P1[j].y);
        const float2 hi1 = make_float2(P1[j].z, P1[j].w);
        const float2 ex0_1 = s1[j] ? hi1 : lo1;
        const float2 ex1_1 = o1 ? A1[j] : (s1[j] ? lo1 : hi1);
        ax1 = fmaf(w1[2*j],   ex0_1.x, ax1);
        ay1 = fmaf(w1[2*j],   ex0_1.y, ay1);
        ax1 = fmaf(w1[2*j+1], ex1_1.x, ax1);
        ay1 = fmaf(w1[2*j+1], ex1_1.y, ay1);
    }
    lslab[b0] = make_float2(ax0, ay0);
    lslab[b1] = make_float2(ax1, ay1);
}

// ws [L][B] float2 (level-major) -> out [B][8] float4 (level-interleaved)
// chunk-per-thread: thread g writes exactly one float4 (fully coalesced)
__global__ __launch_bounds__(256) void interleave_kernel(
    const float2* __restrict__ ws, float4* __restrict__ out, int B)
{
    const int g = blockIdx.x * blockDim.x + threadIdx.x;
    if (g >= B * 8) return;
    const int p = g >> 3;        // point
    const int c = g & 7;         // float4 chunk = levels (2c, 2c+1)
    const float2 v0 = ws[(size_t)(2 * c)     * B + p];
    const float2 v1 = ws[(size_t)(2 * c + 1) * B + p];
    out[g] = make_float4(v0.x, v0.y, v1.x, v1.y);
}

// ---------------- fallback: round-1 flat kernel (proven correct) -----------
__device__ __forceinline__ void encode_point(
    float x, float y, float z, float scale, uint32_t mask, uint32_t off,
    uint32_t rows[8], float ws[8])
{
    const float px = __fadd_rn(__fmul_rn(x, scale), 0.5f);
    const float py = __fadd_rn(__fmul_rn(y, scale), 0.5f);
    const float pz = __fadd_rn(__fmul_rn(z, scale), 0.5f);
    const float fx0 = floorf(px), fy0 = floorf(py), fz0 = floorf(pz);
    const uint32_t X0 = (uint32_t)fx0;
    const uint32_t Y0 = (uint32_t)fy0;
    const uint32_t Z0 = (uint32_t)fz0;
    const float fx = px - fx0, fy = py - fy0, fz = pz - fz0;

    const uint32_t hx0 = X0,      hx1 = X0 + 1u;
    const uint32_t hy0 = Y0 * P1, hy1 = hy0 + P1;
    const uint32_t hz0 = Z0 * P2, hz1 = hz0 + P2;

    rows[0] = ((hx0 ^ hy0 ^ hz0) & mask) + off;
    rows[1] = ((hx1 ^ hy0 ^ hz0) & mask) + off;
    rows[2] = ((hx0 ^ hy1 ^ hz0) & mask) + off;
    rows[3] = ((hx1 ^ hy1 ^ hz0) & mask) + off;
    rows[4] = ((hx0 ^ hy0 ^ hz1) & mask) + off;
    rows[5] = ((hx1 ^ hy0 ^ hz1) & mask) + off;
    rows[6] = ((hx0 ^ hy1 ^ hz1) & mask) + off;
    rows[7] = ((hx1 ^ hy1 ^ hz1) & mask) + off;

    const float wx1 = fx, wx0 = 1.0f - fx;
    const float wy1 = fy, wy0 = 1.0f - fy;
    const float wz1 = fz, wz0 = 1.0f - fz;
    const float wy0z0 = wy0 * wz0, wy1z0 = wy1 * wz0;
    const float wy0z1 = wy0 * wz1, wy1z1 = wy1 * wz1;
    ws[0] = wx0 * wy0z0; ws[1] = wx1 * wy0z0;
    ws[2] = wx0 * wy1z0; ws[3] = wx1 * wy1z0;
    ws[4] = wx0 * wy0z1; ws[5] = wx1 * wy0z1;
    ws[6] = wx0 * wy1z1; ws[7] = wx1 * wy1z1;
}

__global__ __launch_bounds__(256) void grid_encode_flat(
    const float* __restrict__ inp, const float* __restrict__ emb,
    float* __restrict__ out, int B)
{
    const int b = blockIdx.x * blockDim.x + threadIdx.x;
    if (b >= B) return;
    const float x = (inp[3 * b + 0] + 1.0f) * 0.5f;
    const float y = (inp[3 * b + 1] + 1.0f) * 0.5f;
    const float z = (inp[3 * b + 2] + 1.0f) * 0.5f;
    const float2* etab = (const float2*)emb;
    float res[2 * NLEV];
    #pragma unroll
    for (int l = 0; l < NLEV; ++l) {
        uint32_t rows[8]; float wts[8];
        encode_point(x, y, z, dScale[l], dMask[l], dOff[l], rows, wts);
        float2 e[8];
        #pragma unroll
        for (int c = 0; c < 8; ++c) e[c] = etab[rows[c]];
        float ax = 0.f, ay = 0.f;
        #pragma unroll
        for (int c = 0; c < 8; ++c) { ax = fmaf(wts[c], e[c].x, ax); ay = fmaf(wts[c], e[c].y, ay); }
        res[2 * l + 0] = ax; res[2 * l + 1] = ay;
    }
    float4* o4 = (float4*)(out + (size_t)b * (2 * NLEV));
    #pragma unroll
    for (int k = 0; k < 8; ++k)
        o4[k] = make_float4(res[4 * k + 0], res[4 * k + 1], res[4 * k + 2], res[4 * k + 3]);
}

extern "C" void kernel_launch(void* const* d_in, const int* in_sizes, int n_in,
                              void* d_out, int out_size, void* d_ws, size_t ws_size,
                              hipStream_t stream) {
    const float* inp = (const float*)d_in[0];   // [B,3] float32
    const float* emb = (const float*)d_in[1];   // [total_rows,2] float32
    float* out = (float*)d_out;                 // [B,32] float32
    const int B = in_sizes[0] / 3;

    const size_t need = (size_t)B * NLEV * 2 * sizeof(float);
    if (ws_size >= need && (B & 1) == 0) {
        float2* ws = (float2*)d_ws;
        const float2* etab = (const float2*)emb;
        const int half = B >> 1;
        dim3 gridL((half + 255) / 256, NLEV);
        levels_fused_kernel<<<gridL, 256, 0, stream>>>(inp, etab, ws, B);
        const int blkI = (B * 8 + 255) / 256;
        interleave_kernel<<<blkI, 256, 0, stream>>>(ws, (float4*)out, B);
    } else {
        const int blk = (B + 255) / 256;
        grid_encode_flat<<<blk, 256, 0, stream>>>(inp, emb, out, B);
    }
}

// Round 7
// 488.328 us; speedup vs baseline: 1.2046x; 1.2046x over previous
//
#include <hip/hip_runtime.h>
#include <stdint.h>

// GridEncoder (instant-ngp hash grid), D=3, L=16, C=2, H=16, PLS=2, log2_hash=19.
// Round 7: corner-pair coalescing, spill-free. Round 6 proved the mechanism
// (PRIMES[0]==1 -> even X0 makes the two x-corners an aligned {r, r^1} float4
// pair; 6 lines/point-level vs 8) but 2 points/thread + launch_bounds(256,8)
// spilled to scratch (WRITE_SIZE 131->524MB, FETCH +520MB) and regressed.
// This round: 1 point/thread (live set ~36 VGPR < 64 cap), identical FMA
// order (bit-identical output), same round-3 skeleton (blockIdx.y = level,
// level-major slab + coalesced interleave pass).
// Round-5/6 evidence: gather phase is request-rate capped (~0.42 lines/cyc/CU,
// 18% HBM BW with 3TB/s headroom demonstrated) -> request count is the lever.

#define NLEV 16

__constant__ uint32_t dOff[NLEV] = {
    0u, 4096u, 36864u, 299008u, 823296u, 1347584u, 1871872u, 2396160u,
    2920448u, 3444736u, 3969024u, 4493312u, 5017600u, 5541888u,
    6066176u, 6590464u };
__constant__ uint32_t dMask[NLEV] = {
    4095u, 32767u, 262143u, 524287u, 524287u, 524287u, 524287u, 524287u,
    524287u, 524287u, 524287u, 524287u, 524287u, 524287u, 524287u, 524287u };
__constant__ float dScale[NLEV] = {
    15.f, 31.f, 63.f, 127.f, 255.f, 511.f, 1023.f, 2047.f,
    4095.f, 8191.f, 16383.f, 32767.f, 65535.f, 131071.f, 262143.f, 524287.f };

constexpr uint32_t P1 = 2654435761u, P2 = 805459861u;

// pair[j]: 16B-aligned row (incl. off) whose slot sel[j] holds corner x0
//          (and slot 1-sel[j] holds corner x1 iff X0 even)
// alt[j] : row (incl. off) of corner x1, needed only when X0 odd
__device__ __forceinline__ void encode_pairs(
    float x, float y, float z, float scale, uint32_t mask, uint32_t off,
    uint32_t pair[4], uint32_t alt[4], uint32_t sel[4], bool& odd, float w[8])
{
    const float px = __fadd_rn(__fmul_rn(x, scale), 0.5f);
    const float py = __fadd_rn(__fmul_rn(y, scale), 0.5f);
    const float pz = __fadd_rn(__fmul_rn(z, scale), 0.5f);
    const float fx0 = floorf(px), fy0 = floorf(py), fz0 = floorf(pz);
    const uint32_t X0 = (uint32_t)fx0;
    const uint32_t Y0 = (uint32_t)fy0;
    const uint32_t Z0 = (uint32_t)fz0;
    const float fx = px - fx0, fy = py - fy0, fz = pz - fz0;

    const uint32_t hx0 = X0,      hx1 = X0 + 1u;
    const uint32_t hy0 = Y0 * P1, hy1 = hy0 + P1;
    const uint32_t hz0 = Z0 * P2, hz1 = hz0 + P2;

    odd = (X0 & 1u) != 0u;
    const uint32_t hyz[4] = { hy0 ^ hz0, hy1 ^ hz0, hy0 ^ hz1, hy1 ^ hz1 };
    #pragma unroll
    for (int j = 0; j < 4; ++j) {
        const uint32_t r0 = (hx0 ^ hyz[j]) & mask;
        pair[j] = (r0 & ~1u) + off;
        sel[j]  = r0 & 1u;
        alt[j]  = ((hx1 ^ hyz[j]) & mask) + off;
    }

    const float wx1 = fx, wx0 = 1.0f - fx;
    const float wy1 = fy, wy0 = 1.0f - fy;
    const float wz1 = fz, wz0 = 1.0f - fz;
    const float wy0z0 = wy0 * wz0, wy1z0 = wy1 * wz0;
    const float wy0z1 = wy0 * wz1, wy1z1 = wy1 * wz1;
    w[0] = wx0 * wy0z0; w[1] = wx1 * wy0z0;
    w[2] = wx0 * wy1z0; w[3] = wx1 * wy1z0;
    w[4] = wx0 * wy0z1; w[5] = wx1 * wy0z1;
    w[6] = wx0 * wy1z1; w[7] = wx1 * wy1z1;
}

// all levels in one dispatch: blockIdx.y = level; ONE point per thread
__global__ __launch_bounds__(256, 8) void levels_fused_kernel(
    const float* __restrict__ inp,   // [B,3]
    const float2* __restrict__ etab, // [total_rows]
    float2* __restrict__ slab,       // [NLEV][B]
    int B)
{
    const int lvl = blockIdx.y;
    const float    scale = dScale[lvl];
    const uint32_t mask  = dMask[lvl];
    const uint32_t off   = dOff[lvl];
    float2* __restrict__ lslab = slab + (size_t)lvl * B;

    const int t = blockIdx.x * blockDim.x + threadIdx.x;
    if (t >= B) return;

    const float x = (inp[3 * t + 0] + 1.0f) * 0.5f;
    const float y = (inp[3 * t + 1] + 1.0f) * 0.5f;
    const float z = (inp[3 * t + 2] + 1.0f) * 0.5f;

    uint32_t pair[4], alt[4], sel[4]; bool odd; float w[8];
    encode_pairs(x, y, z, scale, mask, off, pair, alt, sel, odd, w);

    // pair loads: one 16B line-resident float4 covers both x-corners (even X0)
    float4 P[4];
    #pragma unroll
    for (int j = 0; j < 4; ++j)
        P[j] = *reinterpret_cast<const float4*>(etab + pair[j]);

    // odd-X0 lanes fetch the x1 corner separately (exec-masked loads)
    float2 A[4] = {make_float2(0.f,0.f), make_float2(0.f,0.f),
                   make_float2(0.f,0.f), make_float2(0.f,0.f)};
    if (odd) {
        #pragma unroll
        for (int j = 0; j < 4; ++j) A[j] = etab[alt[j]];
    }

    // consume: identical weight/fma order to rounds 1-6 (corners 0..7)
    float ax = 0.f, ay = 0.f;
    #pragma unroll
    for (int j = 0; j < 4; ++j) {
        const float2 lo = make_float2(P[j].x, P[j].y);
        const float2 hi = make_float2(P[j].z, P[j].w);
        const float2 e0 = sel[j] ? hi : lo;
        const float2 e1 = odd ? A[j] : (sel[j] ? lo : hi);
        ax = fmaf(w[2*j],   e0.x, ax);
        ay = fmaf(w[2*j],   e0.y, ay);
        ax = fmaf(w[2*j+1], e1.x, ax);
        ay = fmaf(w[2*j+1], e1.y, ay);
    }
    lslab[t] = make_float2(ax, ay);
}

// ws [L][B] float2 (level-major) -> out [B][8] float4 (level-interleaved)
// chunk-per-thread: thread g writes exactly one float4 (fully coalesced)
__global__ __launch_bounds__(256) void interleave_kernel(
    const float2* __restrict__ ws, float4* __restrict__ out, int B)
{
    const int g = blockIdx.x * blockDim.x + threadIdx.x;
    if (g >= B * 8) return;
    const int p = g >> 3;        // point
    const int c = g & 7;         // float4 chunk = levels (2c, 2c+1)
    const float2 v0 = ws[(size_t)(2 * c)     * B + p];
    const float2 v1 = ws[(size_t)(2 * c + 1) * B + p];
    out[g] = make_float4(v0.x, v0.y, v1.x, v1.y);
}

// ---------------- fallback: round-1 flat kernel (proven correct) -----------
__device__ __forceinline__ void encode_point(
    float x, float y, float z, float scale, uint32_t mask, uint32_t off,
    uint32_t rows[8], float ws[8])
{
    const float px = __fadd_rn(__fmul_rn(x, scale), 0.5f);
    const float py = __fadd_rn(__fmul_rn(y, scale), 0.5f);
    const float pz = __fadd_rn(__fmul_rn(z, scale), 0.5f);
    const float fx0 = floorf(px), fy0 = floorf(py), fz0 = floorf(pz);
    const uint32_t X0 = (uint32_t)fx0;
    const uint32_t Y0 = (uint32_t)fy0;
    const uint32_t Z0 = (uint32_t)fz0;
    const float fx = px - fx0, fy = py - fy0, fz = pz - fz0;

    const uint32_t hx0 = X0,      hx1 = X0 + 1u;
    const uint32_t hy0 = Y0 * P1, hy1 = hy0 + P1;
    const uint32_t hz0 = Z0 * P2, hz1 = hz0 + P2;

    rows[0] = ((hx0 ^ hy0 ^ hz0) & mask) + off;
    rows[1] = ((hx1 ^ hy0 ^ hz0) & mask) + off;
    rows[2] = ((hx0 ^ hy1 ^ hz0) & mask) + off;
    rows[3] = ((hx1 ^ hy1 ^ hz0) & mask) + off;
    rows[4] = ((hx0 ^ hy0 ^ hz1) & mask) + off;
    rows[5] = ((hx1 ^ hy0 ^ hz1) & mask) + off;
    rows[6] = ((hx0 ^ hy1 ^ hz1) & mask) + off;
    rows[7] = ((hx1 ^ hy1 ^ hz1) & mask) + off;

    const float wx1 = fx, wx0 = 1.0f - fx;
    const float wy1 = fy, wy0 = 1.0f - fy;
    const float wz1 = fz, wz0 = 1.0f - fz;
    const float wy0z0 = wy0 * wz0, wy1z0 = wy1 * wz0;
    const float wy0z1 = wy0 * wz1, wy1z1 = wy1 * wz1;
    ws[0] = wx0 * wy0z0; ws[1] = wx1 * wy0z0;
    ws[2] = wx0 * wy1z0; ws[3] = wx1 * wy1z0;
    ws[4] = wx0 * wy0z1; ws[5] = wx1 * wy0z1;
    ws[6] = wx0 * wy1z1; ws[7] = wx1 * wy1z1;
}

__global__ __launch_bounds__(256) void grid_encode_flat(
    const float* __restrict__ inp, const float* __restrict__ emb,
    float* __restrict__ out, int B)
{
    const int b = blockIdx.x * blockDim.x + threadIdx.x;
    if (b >= B) return;
    const float x = (inp[3 * b + 0] + 1.0f) * 0.5f;
    const float y = (inp[3 * b + 1] + 1.0f) * 0.5f;
    const float z = (inp[3 * b + 2] + 1.0f) * 0.5f;
    const float2* etab = (const float2*)emb;
    float res[2 * NLEV];
    #pragma unroll
    for (int l = 0; l < NLEV; ++l) {
        uint32_t rows[8]; float wts[8];
        encode_point(x, y, z, dScale[l], dMask[l], dOff[l], rows, wts);
        float2 e[8];
        #pragma unroll
        for (int c = 0; c < 8; ++c) e[c] = etab[rows[c]];
        float ax = 0.f, ay = 0.f;
        #pragma unroll
        for (int c = 0; c < 8; ++c) { ax = fmaf(wts[c], e[c].x, ax); ay = fmaf(wts[c], e[c].y, ay); }
        res[2 * l + 0] = ax; res[2 * l + 1] = ay;
    }
    float4* o4 = (float4*)(out + (size_t)b * (2 * NLEV));
    #pragma unroll
    for (int k = 0; k < 8; ++k)
        o4[k] = make_float4(res[4 * k + 0], res[4 * k + 1], res[4 * k + 2], res[4 * k + 3]);
}

extern "C" void kernel_launch(void* const* d_in, const int* in_sizes, int n_in,
                              void* d_out, int out_size, void* d_ws, size_t ws_size,
                              hipStream_t stream) {
    const float* inp = (const float*)d_in[0];   // [B,3] float32
    const float* emb = (const float*)d_in[1];   // [total_rows,2] float32
    float* out = (float*)d_out;                 // [B,32] float32
    const int B = in_sizes[0] / 3;

    const size_t need = (size_t)B * NLEV * 2 * sizeof(float);
    if (ws_size >= need) {
        float2* ws = (float2*)d_ws;
        const float2* etab = (const float2*)emb;
        dim3 gridL((B + 255) / 256, NLEV);
        levels_fused_kernel<<<gridL, 256, 0, stream>>>(inp, etab, ws, B);
        const int blkI = (B * 8 + 255) / 256;
        interleave_kernel<<<blkI, 256, 0, stream>>>(ws, (float4*)out, B);
    } else {
        const int blk = (B + 255) / 256;
        grid_encode_flat<<<blk, 256, 0, stream>>>(inp, emb, out, B);
    }
}